// Round 1
// baseline (35549.771 us; speedup 1.0000x reference)
//
#include <hip/hip_runtime.h>
#include <hip/hip_bf16.h>
#include <stdint.h>
#include <stddef.h>

typedef unsigned short ushort_t;
typedef unsigned int uint_t;

typedef __attribute__((ext_vector_type(8))) short short8;
typedef __attribute__((ext_vector_type(4))) float floatx4;
typedef __attribute__((ext_vector_type(4))) uint_t uintx4;

#define N_ROWS 32768
#define K_ENT  8192
#define CDIM   256
#define OUT_ELEMS 8388608
#define LOSS_OFF  8388608
#define IDX_OFF   8388609
#define SURV_CAP  32
#define MARGIN    1.0e-3f

// workspace byte offsets
#define WS_ZSW    0            // ushort[N_ROWS*CDIM]  16,777,216 B (swizzled bf16 z)
#define WS_CBSW   16777216     // ushort[K_ENT*CDIM]    4,194,304 B (swizzled bf16 codebook)
#define WS_SURV   20971520     // int[N_ROWS*SURV_CAP]  4,194,304 B
#define WS_CNT    25165824     // int[N_ROWS]             131,072 B
#define WS_IDX    25296896     // int[N_ROWS]             131,072 B
#define WS_ACC    25427968     // double loss accumulator

// RNE float -> bf16 bits
__device__ __forceinline__ ushort_t f2bf(float f) {
    uint_t x = __float_as_uint(f);
    uint_t r = (x + 0x7fffu + ((x >> 16) & 1u)) >> 16;
    return (ushort_t)r;
}

// Swizzled layout: element (row, c) lives at
//   (row>>4)*4096 + (c>>5)*512 + ((c>>3)&3)*128 + (row&15)*8 + (c&7)   [ushort index]
// so that a wave's MFMA fragment load (lane l reads row-group row16=(l&15),
// c-offset (l>>4)*8, 8 bf16 = 16 B) is a single contiguous 1 KiB per (rowgroup, cc).

__global__ void k_init(int* __restrict__ cnt, double* __restrict__ acc) {
    int t = blockIdx.x * 256 + threadIdx.x;
    if (t < N_ROWS) cnt[t] = 0;
    if (t == 0) *acc = 0.0;
}

__global__ __launch_bounds__(256) void k_conv_cb(const float* __restrict__ cb,
                                                 ushort_t* __restrict__ cbsw) {
    int t = blockIdx.x * 256 + threadIdx.x;   // 262,144 threads: (ent, c-chunk of 8)
    int ent = t >> 5;
    int c0  = (t & 31) << 3;
    const float* p = cb + (size_t)ent * CDIM + c0;
    floatx4 f0 = *(const floatx4*)p;
    floatx4 f1 = *(const floatx4*)(p + 4);
    uintx4 pk;
    pk[0] = (uint_t)f2bf(f0[0]) | ((uint_t)f2bf(f0[1]) << 16);
    pk[1] = (uint_t)f2bf(f0[2]) | ((uint_t)f2bf(f0[3]) << 16);
    pk[2] = (uint_t)f2bf(f1[0]) | ((uint_t)f2bf(f1[1]) << 16);
    pk[3] = (uint_t)f2bf(f1[2]) | ((uint_t)f2bf(f1[3]) << 16);
    int idx = (ent >> 4) * 4096 + (c0 >> 5) * 512 + ((c0 >> 3) & 3) * 128 + (ent & 15) * 8;
    *(uintx4*)(cbsw + idx) = pk;
}

// z[b][c][s] -> swizzled bf16 z_flat[n=b*4096+s][c], via LDS transpose tile 64c x 64s
__global__ __launch_bounds__(256) void k_conv_z(const float* __restrict__ zin,
                                                ushort_t* __restrict__ zsw) {
    __shared__ float lds[64][65];
    int bid = blockIdx.x;
    int c0 = (bid & 3) << 6;
    int s0 = ((bid >> 2) & 63) << 6;
    int b  = bid >> 8;
    int tid = threadIdx.x;
    int j = tid & 63, ib = tid >> 6;
    const float* zb = zin + ((size_t)b << 20);
#pragma unroll
    for (int rr = 0; rr < 16; ++rr) {
        int i = rr * 4 + ib;                       // c-local
        lds[i][j] = zb[(size_t)(c0 + i) * 4096 + s0 + j];   // coalesced over j
    }
    __syncthreads();
#pragma unroll
    for (int it = 0; it < 2; ++it) {
        int item = it * 256 + tid;                 // 512 items: (s-local, c-chunk)
        int sl = item >> 3;
        int ch = item & 7;
        int row = (b << 12) + s0 + sl;             // n
        int cg  = c0 + ch * 8;
        uintx4 pk;
#pragma unroll
        for (int q = 0; q < 4; ++q) {
            ushort_t lo = f2bf(lds[ch * 8 + 2 * q][sl]);
            ushort_t hi = f2bf(lds[ch * 8 + 2 * q + 1][sl]);
            pk[q] = (uint_t)lo | ((uint_t)hi << 16);
        }
        int idx = (row >> 4) * 4096 + (cg >> 5) * 512 + ((cg >> 3) & 3) * 128 + (row & 15) * 8;
        *(uintx4*)(zsw + idx) = pk;
    }
}

// bf16 MFMA screen: block = 64 rows x all K. wave w: row-half (w&1), k-half (w>>1).
// Appends every k with dot >= running_rowmax - MARGIN to the row's survivor list.
__global__ __launch_bounds__(256, 2) void k_screen(const ushort_t* __restrict__ zsw,
                                                   const ushort_t* __restrict__ cbsw,
                                                   int* __restrict__ surv,
                                                   int* __restrict__ cnt) {
    int tid = threadIdx.x;
    int w = tid >> 6, l = tid & 63;
    int lo8 = l * 8;
    int g = l >> 4, e = l & 15;
    int RB = blockIdx.x * 64;
    int rh = w & 1, kh = w >> 1;

    short8 afr[2][8];
#pragma unroll
    for (int m = 0; m < 2; ++m) {
        int rg = (RB >> 4) + rh * 2 + m;
        const ushort_t* pa = zsw + (size_t)rg * 4096 + lo8;
#pragma unroll
        for (int cc = 0; cc < 8; ++cc)
            afr[m][cc] = *(const short8*)(pa + cc * 512);
    }
    float rmx[2][4];
#pragma unroll
    for (int m = 0; m < 2; ++m)
#pragma unroll
        for (int r = 0; r < 4; ++r) rmx[m][r] = -3.0e38f;

    for (int kt = 0; kt < 128; ++kt) {
        const ushort_t* pb = cbsw + (size_t)(kt * 4 + kh * 2) * 4096 + lo8;
        floatx4 acc[2][2];
        acc[0][0] = (floatx4){0.f, 0.f, 0.f, 0.f};
        acc[0][1] = (floatx4){0.f, 0.f, 0.f, 0.f};
        acc[1][0] = (floatx4){0.f, 0.f, 0.f, 0.f};
        acc[1][1] = (floatx4){0.f, 0.f, 0.f, 0.f};
#pragma unroll
        for (int cc = 0; cc < 8; ++cc) {
            short8 b0 = *(const short8*)(pb + cc * 512);
            short8 b1 = *(const short8*)(pb + 4096 + cc * 512);
            acc[0][0] = __builtin_amdgcn_mfma_f32_16x16x32_bf16(afr[0][cc], b0, acc[0][0], 0, 0, 0);
            acc[1][0] = __builtin_amdgcn_mfma_f32_16x16x32_bf16(afr[1][cc], b0, acc[1][0], 0, 0, 0);
            acc[0][1] = __builtin_amdgcn_mfma_f32_16x16x32_bf16(afr[0][cc], b1, acc[0][1], 0, 0, 0);
            acc[1][1] = __builtin_amdgcn_mfma_f32_16x16x32_bf16(afr[1][cc], b1, acc[1][1], 0, 0, 0);
        }
        int ent0 = (kt * 4 + kh * 2) * 16 + e;   // nn=0 entry; nn=1 is +16
#pragma unroll
        for (int m = 0; m < 2; ++m) {
            int nrow_base = RB + rh * 32 + m * 16 + g * 4;
#pragma unroll
            for (int r = 0; r < 4; ++r) {
                float v0 = acc[m][0][r], v1 = acc[m][1][r];
                float mx = fmaxf(v0, v1);
                mx = fmaxf(mx, __shfl_xor(mx, 1));
                mx = fmaxf(mx, __shfl_xor(mx, 2));
                mx = fmaxf(mx, __shfl_xor(mx, 4));
                mx = fmaxf(mx, __shfl_xor(mx, 8));
                float rm = fmaxf(rmx[m][r], mx);
                rmx[m][r] = rm;
                float thr = rm - MARGIN;
                if (v0 >= thr) {
                    int n = nrow_base + r;
                    int s = atomicAdd(&cnt[n], 1);
                    if (s < SURV_CAP) surv[n * SURV_CAP + s] = ent0;
                }
                if (v1 >= thr) {
                    int n = nrow_base + r;
                    int s = atomicAdd(&cnt[n], 1);
                    if (s < SURV_CAP) surv[n * SURV_CAP + s] = ent0 + 16;
                }
            }
        }
    }
}

// Exact fp32 refine: replicate u = fl(znorm - fl(2*dot)) argmin with first-index ties.
__global__ __launch_bounds__(256) void k_refine(const float* __restrict__ zin,
                                                const float* __restrict__ cb,
                                                const int* __restrict__ surv,
                                                const int* __restrict__ cnt,
                                                int* __restrict__ idxi,
                                                float* __restrict__ idxf) {
    __shared__ float zr[4][256];
    int w = threadIdx.x >> 6, l = threadIdx.x & 63;
    int n = blockIdx.x * 4 + w;
    int b = n >> 12, s = n & 4095;
    const float* zb = zin + ((size_t)b << 20) + s;
#pragma unroll
    for (int i = 0; i < 4; ++i)
        zr[w][l + 64 * i] = zb[(size_t)(l + 64 * i) << 12];
    __syncthreads();
    const float* z = zr[w];
    float zn = 0.f;
    for (int c = 0; c < 256; ++c) zn = fmaf(z[c], z[c], zn);

    int m = cnt[n];
    float bu = 3.0e38f;
    int bk = 0x7fffffff;
    if (m >= 1 && m <= SURV_CAP) {
        if (l < m) {
            int k = surv[n * SURV_CAP + l];
            const float* cr = cb + (size_t)k * 256;
            float d = 0.f;
            for (int c = 0; c < 256; c += 4) {
                floatx4 wv = *(const floatx4*)(cr + c);
                d = fmaf(z[c], wv[0], d);
                d = fmaf(z[c + 1], wv[1], d);
                d = fmaf(z[c + 2], wv[2], d);
                d = fmaf(z[c + 3], wv[3], d);
            }
            bu = zn - 2.0f * d;
            bk = k;
        }
    } else {
        // fallback: exact scan of all K (rare: overflowed or empty survivor list)
        for (int k = l; k < K_ENT; k += 64) {
            const float* cr = cb + (size_t)k * 256;
            float d = 0.f;
            for (int c = 0; c < 256; c += 4) {
                floatx4 wv = *(const floatx4*)(cr + c);
                d = fmaf(z[c], wv[0], d);
                d = fmaf(z[c + 1], wv[1], d);
                d = fmaf(z[c + 2], wv[2], d);
                d = fmaf(z[c + 3], wv[3], d);
            }
            float u = zn - 2.0f * d;
            if (u < bu) { bu = u; bk = k; }   // ascending k keeps first min
        }
    }
#pragma unroll
    for (int msk = 1; msk < 64; msk <<= 1) {
        float ou = __shfl_xor(bu, msk);
        int   ok = __shfl_xor(bk, msk);
        if (ou < bu || (ou == bu && ok < bk)) { bu = ou; bk = ok; }
    }
    if (l == 0) { idxi[n] = bk; idxf[n] = (float)bk; }
}

// Gather z_q to output (coalesced writes) + loss partial sums
__global__ __launch_bounds__(256) void k_gather(const float* __restrict__ zin,
                                                const float* __restrict__ cb,
                                                const int* __restrict__ idxi,
                                                float* __restrict__ out,
                                                double* __restrict__ acc) {
    __shared__ float wsum[4];
    int t = blockIdx.x * 256 + threadIdx.x;   // 2,097,152 threads, 4 elems each
    int o = t << 2;
    int b = o >> 20, rem = o & 1048575;
    int c = rem >> 12, sp = rem & 4095;
    int n = (b << 12) + sp;
    floatx4 z4 = *(const floatx4*)(zin + o);
    floatx4 v;
    float ls = 0.f;
#pragma unroll
    for (int i = 0; i < 4; ++i) {
        int k = idxi[n + i];
        float cv = cb[(size_t)k * 256 + c];
        v[i] = cv;
        float d = cv - z4[i];
        ls = fmaf(d, d, ls);
    }
    *(floatx4*)(out + o) = v;
#pragma unroll
    for (int msk = 1; msk < 64; msk <<= 1) ls += __shfl_xor(ls, msk);
    int w = threadIdx.x >> 6, l = threadIdx.x & 63;
    if (l == 0) wsum[w] = ls;
    __syncthreads();
    if (threadIdx.x == 0) {
        float tot = (wsum[0] + wsum[1]) + (wsum[2] + wsum[3]);
        atomicAdd(acc, (double)tot);
    }
}

__global__ void k_fin(const double* __restrict__ acc, float* __restrict__ out) {
    out[LOSS_OFF] = (float)(2.0 * (*acc) / 8388608.0);
}

extern "C" void kernel_launch(void* const* d_in, const int* in_sizes, int n_in,
                              void* d_out, int out_size, void* d_ws, size_t ws_size,
                              hipStream_t stream) {
    (void)in_sizes; (void)n_in; (void)out_size; (void)ws_size;
    const float* z  = (const float*)d_in[0];
    const float* cb = (const float*)d_in[1];
    float* out = (float*)d_out;
    char* ws = (char*)d_ws;
    ushort_t* zsw  = (ushort_t*)(ws + WS_ZSW);
    ushort_t* cbsw = (ushort_t*)(ws + WS_CBSW);
    int* surv = (int*)(ws + WS_SURV);
    int* cnt  = (int*)(ws + WS_CNT);
    int* idxi = (int*)(ws + WS_IDX);
    double* acc = (double*)(ws + WS_ACC);

    k_init<<<128, 256, 0, stream>>>(cnt, acc);
    k_conv_cb<<<1024, 256, 0, stream>>>(cb, cbsw);
    k_conv_z<<<2048, 256, 0, stream>>>(z, zsw);
    k_screen<<<512, 256, 0, stream>>>(zsw, cbsw, surv, cnt);
    k_refine<<<8192, 256, 0, stream>>>(z, cb, surv, cnt, idxi, out + IDX_OFF);
    k_gather<<<8192, 256, 0, stream>>>(z, cb, idxi, out, acc);
    k_fin<<<1, 1, 0, stream>>>(acc, out);
}

// Round 2
// 2719.402 us; speedup vs baseline: 13.0726x; 13.0726x over previous
//
#include <hip/hip_runtime.h>
#include <hip/hip_bf16.h>
#include <stdint.h>
#include <stddef.h>

typedef unsigned short ushort_t;
typedef unsigned int uint_t;

typedef __attribute__((ext_vector_type(8))) short short8;
typedef __attribute__((ext_vector_type(4))) float floatx4;
typedef __attribute__((ext_vector_type(4))) uint_t uintx4;

#define N_ROWS 32768
#define K_ENT  8192
#define CDIM   256
#define OUT_ELEMS 8388608
#define LOSS_OFF  8388608
#define IDX_OFF   8388609
#define SURV_CAP  32
// Screen margin: covers bf16 rounding of z,c (aligned-worst ~5e-5) + reference's
// fp32 quantization quantum ulp(256)=3.05e-5, with ~2.3x headroom. At 0.18 sigma
// of the dot distribution (sigma~1.13e-3) expected survivors are ~2-6 per row.
// (Round-1's 1e-3 was 0.9 sigma -> ~50 survivors -> cap overflow -> full-scan fallback.)
#define MARGIN    2.0e-4f

// RNE float -> bf16 bits
__device__ __forceinline__ ushort_t f2bf(float f) {
    uint_t x = __float_as_uint(f);
    uint_t r = (x + 0x7fffu + ((x >> 16) & 1u)) >> 16;
    return (ushort_t)r;
}

// Swizzled layout: element (row, c) lives at
//   (row>>4)*4096 + (c>>5)*512 + ((c>>3)&3)*128 + (row&15)*8 + (c&7)   [ushort index]
// so a wave's MFMA fragment load (lane l: row16=(l&15), c-off (l>>4)*8, 16 B)
// is a single contiguous 1 KiB per (rowgroup, cc).

__global__ void k_init(int* __restrict__ cnt, double* __restrict__ acc) {
    int t = blockIdx.x * 256 + threadIdx.x;
    if (t < N_ROWS) cnt[t] = 0;
    if (t == 0) *acc = 0.0;
}

__global__ __launch_bounds__(256) void k_conv_cb(const float* __restrict__ cb,
                                                 ushort_t* __restrict__ cbsw) {
    int t = blockIdx.x * 256 + threadIdx.x;   // 262,144 threads: (ent, c-chunk of 8)
    int ent = t >> 5;
    int c0  = (t & 31) << 3;
    const float* p = cb + (size_t)ent * CDIM + c0;
    floatx4 f0 = *(const floatx4*)p;
    floatx4 f1 = *(const floatx4*)(p + 4);
    uintx4 pk;
    pk[0] = (uint_t)f2bf(f0[0]) | ((uint_t)f2bf(f0[1]) << 16);
    pk[1] = (uint_t)f2bf(f0[2]) | ((uint_t)f2bf(f0[3]) << 16);
    pk[2] = (uint_t)f2bf(f1[0]) | ((uint_t)f2bf(f1[1]) << 16);
    pk[3] = (uint_t)f2bf(f1[2]) | ((uint_t)f2bf(f1[3]) << 16);
    int idx = (ent >> 4) * 4096 + (c0 >> 5) * 512 + ((c0 >> 3) & 3) * 128 + (ent & 15) * 8;
    *(uintx4*)(cbsw + idx) = pk;
}

// z[b][c][s] -> swizzled bf16 z_flat[n=b*4096+s][c] (+ optional fp32 transposed copy),
// via LDS transpose tile 64c x 64s
__global__ __launch_bounds__(256) void k_conv_z(const float* __restrict__ zin,
                                                ushort_t* __restrict__ zsw,
                                                float* __restrict__ ztf) {
    __shared__ float lds[64][65];
    int bid = blockIdx.x;
    int c0 = (bid & 3) << 6;
    int s0 = ((bid >> 2) & 63) << 6;
    int b  = bid >> 8;
    int tid = threadIdx.x;
    int j = tid & 63, ib = tid >> 6;
    const float* zb = zin + ((size_t)b << 20);
#pragma unroll
    for (int rr = 0; rr < 16; ++rr) {
        int i = rr * 4 + ib;                       // c-local
        lds[i][j] = zb[(size_t)(c0 + i) * 4096 + s0 + j];   // coalesced over j
    }
    __syncthreads();
#pragma unroll
    for (int it = 0; it < 2; ++it) {
        int item = it * 256 + tid;                 // 512 items: (s-local, c-chunk)
        int sl = item >> 3;
        int ch = item & 7;
        int row = (b << 12) + s0 + sl;             // n
        int cg  = c0 + ch * 8;
        uintx4 pk;
        floatx4 f0, f1;
#pragma unroll
        for (int q = 0; q < 4; ++q) {
            float a = lds[ch * 8 + 2 * q][sl];
            float bqv = lds[ch * 8 + 2 * q + 1][sl];
            pk[q] = (uint_t)f2bf(a) | ((uint_t)f2bf(bqv) << 16);
        }
#pragma unroll
        for (int q = 0; q < 4; ++q) {
            f0[q] = lds[ch * 8 + q][sl];
            f1[q] = lds[ch * 8 + 4 + q][sl];
        }
        int idx = (row >> 4) * 4096 + (cg >> 5) * 512 + ((cg >> 3) & 3) * 128 + (row & 15) * 8;
        *(uintx4*)(zsw + idx) = pk;
        if (ztf) {
            *(floatx4*)(ztf + (size_t)row * 256 + cg) = f0;
            *(floatx4*)(ztf + (size_t)row * 256 + cg + 4) = f1;
        }
    }
}

// bf16 MFMA screen: block = 64 rows x all K. wave w: row-half (w&1), k-half (w>>1).
// Appends every k with dot >= running_rowmax - MARGIN to the row's survivor list.
__global__ __launch_bounds__(256, 2) void k_screen(const ushort_t* __restrict__ zsw,
                                                   const ushort_t* __restrict__ cbsw,
                                                   int* __restrict__ surv,
                                                   int* __restrict__ cnt) {
    int tid = threadIdx.x;
    int w = tid >> 6, l = tid & 63;
    int lo8 = l * 8;
    int g = l >> 4, e = l & 15;
    int RB = blockIdx.x * 64;
    int rh = w & 1, kh = w >> 1;

    short8 afr[2][8];
#pragma unroll
    for (int m = 0; m < 2; ++m) {
        int rg = (RB >> 4) + rh * 2 + m;
        const ushort_t* pa = zsw + (size_t)rg * 4096 + lo8;
#pragma unroll
        for (int cc = 0; cc < 8; ++cc)
            afr[m][cc] = *(const short8*)(pa + cc * 512);
    }
    float rmx[2][4];
#pragma unroll
    for (int m = 0; m < 2; ++m)
#pragma unroll
        for (int r = 0; r < 4; ++r) rmx[m][r] = -3.0e38f;

    for (int kt = 0; kt < 128; ++kt) {
        const ushort_t* pb = cbsw + (size_t)(kt * 4 + kh * 2) * 4096 + lo8;
        floatx4 acc[2][2];
        acc[0][0] = (floatx4){0.f, 0.f, 0.f, 0.f};
        acc[0][1] = (floatx4){0.f, 0.f, 0.f, 0.f};
        acc[1][0] = (floatx4){0.f, 0.f, 0.f, 0.f};
        acc[1][1] = (floatx4){0.f, 0.f, 0.f, 0.f};
#pragma unroll
        for (int cc = 0; cc < 8; ++cc) {
            short8 b0 = *(const short8*)(pb + cc * 512);
            short8 b1 = *(const short8*)(pb + 4096 + cc * 512);
            acc[0][0] = __builtin_amdgcn_mfma_f32_16x16x32_bf16(afr[0][cc], b0, acc[0][0], 0, 0, 0);
            acc[1][0] = __builtin_amdgcn_mfma_f32_16x16x32_bf16(afr[1][cc], b0, acc[1][0], 0, 0, 0);
            acc[0][1] = __builtin_amdgcn_mfma_f32_16x16x32_bf16(afr[0][cc], b1, acc[0][1], 0, 0, 0);
            acc[1][1] = __builtin_amdgcn_mfma_f32_16x16x32_bf16(afr[1][cc], b1, acc[1][1], 0, 0, 0);
        }
        int ent0 = (kt * 4 + kh * 2) * 16 + e;   // nn=0 entry; nn=1 is +16
#pragma unroll
        for (int m = 0; m < 2; ++m) {
            int nrow_base = RB + rh * 32 + m * 16 + g * 4;
#pragma unroll
            for (int r = 0; r < 4; ++r) {
                float v0 = acc[m][0][r], v1 = acc[m][1][r];
                float mx = fmaxf(v0, v1);
                mx = fmaxf(mx, __shfl_xor(mx, 1));
                mx = fmaxf(mx, __shfl_xor(mx, 2));
                mx = fmaxf(mx, __shfl_xor(mx, 4));
                mx = fmaxf(mx, __shfl_xor(mx, 8));
                float rm = fmaxf(rmx[m][r], mx);
                rmx[m][r] = rm;
                float thr = rm - MARGIN;
                if (v0 >= thr) {
                    int n = nrow_base + r;
                    int s = atomicAdd(&cnt[n], 1);
                    if (s < SURV_CAP) surv[n * SURV_CAP + s] = ent0;
                }
                if (v1 >= thr) {
                    int n = nrow_base + r;
                    int s = atomicAdd(&cnt[n], 1);
                    if (s < SURV_CAP) surv[n * SURV_CAP + s] = ent0 + 16;
                }
            }
        }
    }
}

// Exact fp32 refine: replicate u = fl(znorm - fl(2*dot)) argmin with first-index ties.
// One wave per row; one survivor per lane. Summation order identical to round-1's
// passing kernel (serial fmaf chains), so idx semantics are unchanged.
__global__ __launch_bounds__(256) void k_refine(const float* __restrict__ zin,
                                                const float* __restrict__ ztf,
                                                const float* __restrict__ cb,
                                                const int* __restrict__ surv,
                                                const int* __restrict__ cnt,
                                                int* __restrict__ idxi,
                                                float* __restrict__ idxf) {
    __shared__ float zr[4][256];
    int w = threadIdx.x >> 6, l = threadIdx.x & 63;
    int n = blockIdx.x * 4 + w;
    if (ztf) {
        const float* zrow = ztf + (size_t)n * 256;
#pragma unroll
        for (int i = 0; i < 4; ++i)
            zr[w][l + 64 * i] = zrow[l + 64 * i];          // coalesced
    } else {
        int b = n >> 12, s = n & 4095;
        const float* zb = zin + ((size_t)b << 20) + s;
#pragma unroll
        for (int i = 0; i < 4; ++i)
            zr[w][l + 64 * i] = zb[(size_t)(l + 64 * i) << 12];
    }
    __syncthreads();
    const float* z = zr[w];
    float zn = 0.f;
    for (int c = 0; c < 256; ++c) zn = fmaf(z[c], z[c], zn);

    int m = cnt[n];
    float bu = 3.0e38f;
    int bk = 0x7fffffff;
    if (m >= 1 && m <= SURV_CAP) {
        if (l < m) {
            int k = surv[n * SURV_CAP + l];
            const float* cr = cb + (size_t)k * 256;
            float d = 0.f;
            for (int c = 0; c < 256; c += 4) {
                floatx4 wv = *(const floatx4*)(cr + c);
                d = fmaf(z[c], wv[0], d);
                d = fmaf(z[c + 1], wv[1], d);
                d = fmaf(z[c + 2], wv[2], d);
                d = fmaf(z[c + 3], wv[3], d);
            }
            bu = zn - 2.0f * d;
            bk = k;
        }
    } else {
        // fallback: exact scan of all K (cold: only on survivor-list overflow)
        for (int k = l; k < K_ENT; k += 64) {
            const float* cr = cb + (size_t)k * 256;
            float d = 0.f;
            for (int c = 0; c < 256; c += 4) {
                floatx4 wv = *(const floatx4*)(cr + c);
                d = fmaf(z[c], wv[0], d);
                d = fmaf(z[c + 1], wv[1], d);
                d = fmaf(z[c + 2], wv[2], d);
                d = fmaf(z[c + 3], wv[3], d);
            }
            float u = zn - 2.0f * d;
            if (u < bu) { bu = u; bk = k; }   // ascending k keeps first min
        }
    }
#pragma unroll
    for (int msk = 1; msk < 64; msk <<= 1) {
        float ou = __shfl_xor(bu, msk);
        int   ok = __shfl_xor(bk, msk);
        if (ou < bu || (ou == bu && ok < bk)) { bu = ou; bk = ok; }
    }
    if (l == 0) { idxi[n] = bk; idxf[n] = (float)bk; }
}

// Gather z_q to output (coalesced writes) + loss partial sums
__global__ __launch_bounds__(256) void k_gather(const float* __restrict__ zin,
                                                const float* __restrict__ cb,
                                                const int* __restrict__ idxi,
                                                float* __restrict__ out,
                                                double* __restrict__ acc) {
    __shared__ float wsum[4];
    int t = blockIdx.x * 256 + threadIdx.x;   // 2,097,152 threads, 4 elems each
    int o = t << 2;
    int b = o >> 20, rem = o & 1048575;
    int c = rem >> 12, sp = rem & 4095;
    int n = (b << 12) + sp;
    floatx4 z4 = *(const floatx4*)(zin + o);
    floatx4 v;
    float ls = 0.f;
#pragma unroll
    for (int i = 0; i < 4; ++i) {
        int k = idxi[n + i];
        float cv = cb[(size_t)k * 256 + c];
        v[i] = cv;
        float d = cv - z4[i];
        ls = fmaf(d, d, ls);
    }
    *(floatx4*)(out + o) = v;
#pragma unroll
    for (int msk = 1; msk < 64; msk <<= 1) ls += __shfl_xor(ls, msk);
    int w = threadIdx.x >> 6, l = threadIdx.x & 63;
    if (l == 0) wsum[w] = ls;
    __syncthreads();
    if (threadIdx.x == 0) {
        float tot = (wsum[0] + wsum[1]) + (wsum[2] + wsum[3]);
        atomicAdd(acc, (double)tot);
    }
}

__global__ void k_fin(const double* __restrict__ acc, float* __restrict__ out) {
    out[LOSS_OFF] = (float)(2.0 * (*acc) / 8388608.0);
}

extern "C" void kernel_launch(void* const* d_in, const int* in_sizes, int n_in,
                              void* d_out, int out_size, void* d_ws, size_t ws_size,
                              hipStream_t stream) {
    (void)in_sizes; (void)n_in; (void)out_size;
    const float* z  = (const float*)d_in[0];
    const float* cb = (const float*)d_in[1];
    float* out = (float*)d_out;
    char* ws = (char*)d_ws;

    size_t off = 0;
    ushort_t* zsw  = (ushort_t*)(ws + off); off += 16777216;   // bf16 swizzled z
    ushort_t* cbsw = (ushort_t*)(ws + off); off += 4194304;    // bf16 swizzled codebook
    float* ztf = nullptr;
    const size_t ZTF_BYTES = 33554432;                          // fp32 transposed z
    const size_t TAIL = 4194304 + 131072 + 131072 + 8;
    if (ws_size >= off + ZTF_BYTES + TAIL) { ztf = (float*)(ws + off); off += ZTF_BYTES; }
    int* surv = (int*)(ws + off); off += 4194304;
    int* cnt  = (int*)(ws + off); off += 131072;
    int* idxi = (int*)(ws + off); off += 131072;
    double* acc = (double*)(ws + off);

    k_init<<<128, 256, 0, stream>>>(cnt, acc);
    k_conv_cb<<<1024, 256, 0, stream>>>(cb, cbsw);
    k_conv_z<<<2048, 256, 0, stream>>>(z, zsw, ztf);
    k_screen<<<512, 256, 0, stream>>>(zsw, cbsw, surv, cnt);
    k_refine<<<8192, 256, 0, stream>>>(z, ztf, cb, surv, cnt, idxi, out + IDX_OFF);
    k_gather<<<8192, 256, 0, stream>>>(z, cb, idxi, out, acc);
    k_fin<<<1, 1, 0, stream>>>(acc, out);
}

// Round 3
// 869.394 us; speedup vs baseline: 40.8903x; 3.1279x over previous
//
#include <hip/hip_runtime.h>
#include <hip/hip_bf16.h>
#include <stdint.h>
#include <stddef.h>

typedef unsigned short ushort_t;
typedef unsigned int uint_t;

typedef __attribute__((ext_vector_type(8))) short short8;
typedef __attribute__((ext_vector_type(4))) float floatx4;
typedef __attribute__((ext_vector_type(4))) uint_t uintx4;

#define N_ROWS 32768
#define K_ENT  8192
#define CDIM   256
#define OUT_ELEMS 8388608
#define LOSS_OFF  8388608
#define IDX_OFF   8388609
#define SURV_CAP  32
// Screen margin: covers bf16 rounding of z,c (aligned-worst ~5e-5 each side) +
// reference's fp32 quantization quantum ulp(256)=3.05e-5, with headroom.
// Phase B thresholds against the FINAL row max, so survivors = entries genuinely
// within MARGIN of the best => ~1-3 per row (round-2's running-max single pass
// collected ~25 stale near-records/row -> cap overflow -> 2 ms fallback tail).
#define MARGIN    2.0e-4f

// RNE float -> bf16 bits
__device__ __forceinline__ ushort_t f2bf(float f) {
    uint_t x = __float_as_uint(f);
    uint_t r = (x + 0x7fffu + ((x >> 16) & 1u)) >> 16;
    return (ushort_t)r;
}

// Swizzled layout: element (row, c) lives at
//   (row>>4)*4096 + (c>>5)*512 + ((c>>3)&3)*128 + (row&15)*8 + (c&7)   [ushort index]
// so a wave's MFMA fragment load (lane l: row16=(l&15), c-off (l>>4)*8, 16 B)
// is a single contiguous 1 KiB per (rowgroup, cc).

__global__ void k_init(int* __restrict__ cnt, double* __restrict__ acc) {
    int t = blockIdx.x * 256 + threadIdx.x;
    if (t < N_ROWS) cnt[t] = 0;
    if (t == 0) *acc = 0.0;
}

__global__ __launch_bounds__(256) void k_conv_cb(const float* __restrict__ cb,
                                                 ushort_t* __restrict__ cbsw) {
    int t = blockIdx.x * 256 + threadIdx.x;   // 262,144 threads: (ent, c-chunk of 8)
    int ent = t >> 5;
    int c0  = (t & 31) << 3;
    const float* p = cb + (size_t)ent * CDIM + c0;
    floatx4 f0 = *(const floatx4*)p;
    floatx4 f1 = *(const floatx4*)(p + 4);
    uintx4 pk;
    pk[0] = (uint_t)f2bf(f0[0]) | ((uint_t)f2bf(f0[1]) << 16);
    pk[1] = (uint_t)f2bf(f0[2]) | ((uint_t)f2bf(f0[3]) << 16);
    pk[2] = (uint_t)f2bf(f1[0]) | ((uint_t)f2bf(f1[1]) << 16);
    pk[3] = (uint_t)f2bf(f1[2]) | ((uint_t)f2bf(f1[3]) << 16);
    int idx = (ent >> 4) * 4096 + (c0 >> 5) * 512 + ((c0 >> 3) & 3) * 128 + (ent & 15) * 8;
    *(uintx4*)(cbsw + idx) = pk;
}

// z[b][c][s] -> swizzled bf16 z_flat[n=b*4096+s][c] (+ optional fp32 transposed copy),
// via LDS transpose tile 64c x 64s
__global__ __launch_bounds__(256) void k_conv_z(const float* __restrict__ zin,
                                                ushort_t* __restrict__ zsw,
                                                float* __restrict__ ztf) {
    __shared__ float lds[64][65];
    int bid = blockIdx.x;
    int c0 = (bid & 3) << 6;
    int s0 = ((bid >> 2) & 63) << 6;
    int b  = bid >> 8;
    int tid = threadIdx.x;
    int j = tid & 63, ib = tid >> 6;
    const float* zb = zin + ((size_t)b << 20);
#pragma unroll
    for (int rr = 0; rr < 16; ++rr) {
        int i = rr * 4 + ib;                       // c-local
        lds[i][j] = zb[(size_t)(c0 + i) * 4096 + s0 + j];   // coalesced over j
    }
    __syncthreads();
#pragma unroll
    for (int it = 0; it < 2; ++it) {
        int item = it * 256 + tid;                 // 512 items: (s-local, c-chunk)
        int sl = item >> 3;
        int ch = item & 7;
        int row = (b << 12) + s0 + sl;             // n
        int cg  = c0 + ch * 8;
        uintx4 pk;
        floatx4 f0, f1;
#pragma unroll
        for (int q = 0; q < 4; ++q) {
            float a = lds[ch * 8 + 2 * q][sl];
            float bqv = lds[ch * 8 + 2 * q + 1][sl];
            pk[q] = (uint_t)f2bf(a) | ((uint_t)f2bf(bqv) << 16);
        }
#pragma unroll
        for (int q = 0; q < 4; ++q) {
            f0[q] = lds[ch * 8 + q][sl];
            f1[q] = lds[ch * 8 + 4 + q][sl];
        }
        int idx = (row >> 4) * 4096 + (cg >> 5) * 512 + ((cg >> 3) & 3) * 128 + (row & 15) * 8;
        *(uintx4*)(zsw + idx) = pk;
        if (ztf) {
            *(floatx4*)(ztf + (size_t)row * 256 + cg) = f0;
            *(floatx4*)(ztf + (size_t)row * 256 + cg + 4) = f1;
        }
    }
}

// Two-phase bf16 MFMA screen: block = 64 rows x all K. wave w: row-half (w&1),
// k-half (w>>1). Phase A: compute final per-row max dot (per-lane max, one
// shuffle-reduce at the end, cross-wave combine via LDS). Phase B: re-run the
// MFMA sweep, append every k with dot >= final_max - MARGIN.
__global__ __launch_bounds__(256, 2) void k_screen(const ushort_t* __restrict__ zsw,
                                                   const ushort_t* __restrict__ cbsw,
                                                   int* __restrict__ surv,
                                                   int* __restrict__ cnt) {
    __shared__ float smax[2][64];
    int tid = threadIdx.x;
    int w = tid >> 6, l = tid & 63;
    int lo8 = l * 8;
    int g = l >> 4, e = l & 15;
    int RB = blockIdx.x * 64;
    int rh = w & 1, kh = w >> 1;

    short8 afr[2][8];
#pragma unroll
    for (int m = 0; m < 2; ++m) {
        int rg = (RB >> 4) + rh * 2 + m;
        const ushort_t* pa = zsw + (size_t)rg * 4096 + lo8;
#pragma unroll
        for (int cc = 0; cc < 8; ++cc)
            afr[m][cc] = *(const short8*)(pa + cc * 512);
    }

    float rmx[2][4];
#pragma unroll
    for (int m = 0; m < 2; ++m)
#pragma unroll
        for (int r = 0; r < 4; ++r) rmx[m][r] = -3.0e38f;

    // ---- Phase A: max only ----
    for (int kt = 0; kt < 128; ++kt) {
        const ushort_t* pb = cbsw + (size_t)(kt * 4 + kh * 2) * 4096 + lo8;
        floatx4 acc[2][2];
        acc[0][0] = (floatx4){0.f, 0.f, 0.f, 0.f};
        acc[0][1] = (floatx4){0.f, 0.f, 0.f, 0.f};
        acc[1][0] = (floatx4){0.f, 0.f, 0.f, 0.f};
        acc[1][1] = (floatx4){0.f, 0.f, 0.f, 0.f};
#pragma unroll
        for (int cc = 0; cc < 8; ++cc) {
            short8 b0 = *(const short8*)(pb + cc * 512);
            short8 b1 = *(const short8*)(pb + 4096 + cc * 512);
            acc[0][0] = __builtin_amdgcn_mfma_f32_16x16x32_bf16(afr[0][cc], b0, acc[0][0], 0, 0, 0);
            acc[1][0] = __builtin_amdgcn_mfma_f32_16x16x32_bf16(afr[1][cc], b0, acc[1][0], 0, 0, 0);
            acc[0][1] = __builtin_amdgcn_mfma_f32_16x16x32_bf16(afr[0][cc], b1, acc[0][1], 0, 0, 0);
            acc[1][1] = __builtin_amdgcn_mfma_f32_16x16x32_bf16(afr[1][cc], b1, acc[1][1], 0, 0, 0);
        }
#pragma unroll
        for (int m = 0; m < 2; ++m)
#pragma unroll
            for (int r = 0; r < 4; ++r)
                rmx[m][r] = fmaxf(rmx[m][r], fmaxf(acc[m][0][r], acc[m][1][r]));
    }
    // reduce over the 16-lane e-group (masks 1,2,4,8 stay inside the group)
#pragma unroll
    for (int m = 0; m < 2; ++m)
#pragma unroll
        for (int r = 0; r < 4; ++r) {
            float mx = rmx[m][r];
            mx = fmaxf(mx, __shfl_xor(mx, 1));
            mx = fmaxf(mx, __shfl_xor(mx, 2));
            mx = fmaxf(mx, __shfl_xor(mx, 4));
            mx = fmaxf(mx, __shfl_xor(mx, 8));
            rmx[m][r] = mx;
        }
    if (e == 0) {
#pragma unroll
        for (int m = 0; m < 2; ++m)
#pragma unroll
            for (int r = 0; r < 4; ++r)
                smax[kh][rh * 32 + m * 16 + g * 4 + r] = rmx[m][r];
    }
    __syncthreads();
    float thr[2][4];
#pragma unroll
    for (int m = 0; m < 2; ++m)
#pragma unroll
        for (int r = 0; r < 4; ++r) {
            int rl = rh * 32 + m * 16 + g * 4 + r;
            thr[m][r] = fmaxf(smax[0][rl], smax[1][rl]) - MARGIN;
        }

    // ---- Phase B: append vs final-max threshold ----
    for (int kt = 0; kt < 128; ++kt) {
        const ushort_t* pb = cbsw + (size_t)(kt * 4 + kh * 2) * 4096 + lo8;
        floatx4 acc[2][2];
        acc[0][0] = (floatx4){0.f, 0.f, 0.f, 0.f};
        acc[0][1] = (floatx4){0.f, 0.f, 0.f, 0.f};
        acc[1][0] = (floatx4){0.f, 0.f, 0.f, 0.f};
        acc[1][1] = (floatx4){0.f, 0.f, 0.f, 0.f};
#pragma unroll
        for (int cc = 0; cc < 8; ++cc) {
            short8 b0 = *(const short8*)(pb + cc * 512);
            short8 b1 = *(const short8*)(pb + 4096 + cc * 512);
            acc[0][0] = __builtin_amdgcn_mfma_f32_16x16x32_bf16(afr[0][cc], b0, acc[0][0], 0, 0, 0);
            acc[1][0] = __builtin_amdgcn_mfma_f32_16x16x32_bf16(afr[1][cc], b0, acc[1][0], 0, 0, 0);
            acc[0][1] = __builtin_amdgcn_mfma_f32_16x16x32_bf16(afr[0][cc], b1, acc[0][1], 0, 0, 0);
            acc[1][1] = __builtin_amdgcn_mfma_f32_16x16x32_bf16(afr[1][cc], b1, acc[1][1], 0, 0, 0);
        }
        int ent0 = (kt * 4 + kh * 2) * 16 + e;
#pragma unroll
        for (int m = 0; m < 2; ++m) {
            int nrow_base = RB + rh * 32 + m * 16 + g * 4;
#pragma unroll
            for (int r = 0; r < 4; ++r) {
                if (acc[m][0][r] >= thr[m][r]) {
                    int n = nrow_base + r;
                    int s = atomicAdd(&cnt[n], 1);
                    if (s < SURV_CAP) surv[n * SURV_CAP + s] = ent0;
                }
                if (acc[m][1][r] >= thr[m][r]) {
                    int n = nrow_base + r;
                    int s = atomicAdd(&cnt[n], 1);
                    if (s < SURV_CAP) surv[n * SURV_CAP + s] = ent0 + 16;
                }
            }
        }
    }
}

// Exact fp32 refine: replicate u = fl(znorm - fl(2*dot)) argmin with first-index ties.
// One wave per row; one survivor per lane. Serial fmaf order identical to the
// round-1/2 passing kernels, so idx semantics are unchanged.
__global__ __launch_bounds__(256) void k_refine(const float* __restrict__ zin,
                                                const float* __restrict__ ztf,
                                                const float* __restrict__ cb,
                                                const int* __restrict__ surv,
                                                const int* __restrict__ cnt,
                                                int* __restrict__ idxi,
                                                float* __restrict__ idxf) {
    __shared__ float zr[4][256];
    int w = threadIdx.x >> 6, l = threadIdx.x & 63;
    int n = blockIdx.x * 4 + w;
    if (ztf) {
        const float* zrow = ztf + (size_t)n * 256;
#pragma unroll
        for (int i = 0; i < 4; ++i)
            zr[w][l + 64 * i] = zrow[l + 64 * i];          // coalesced
    } else {
        int b = n >> 12, s = n & 4095;
        const float* zb = zin + ((size_t)b << 20) + s;
#pragma unroll
        for (int i = 0; i < 4; ++i)
            zr[w][l + 64 * i] = zb[(size_t)(l + 64 * i) << 12];
    }
    __syncthreads();
    const float* z = zr[w];
    float zn = 0.f;
    for (int c = 0; c < 256; ++c) zn = fmaf(z[c], z[c], zn);

    int m = cnt[n];
    float bu = 3.0e38f;
    int bk = 0x7fffffff;
    if (m >= 1 && m <= SURV_CAP) {
        if (l < m) {
            int k = surv[n * SURV_CAP + l];
            const float* cr = cb + (size_t)k * 256;
            float d = 0.f;
            for (int c = 0; c < 256; c += 4) {
                floatx4 wv = *(const floatx4*)(cr + c);
                d = fmaf(z[c], wv[0], d);
                d = fmaf(z[c + 1], wv[1], d);
                d = fmaf(z[c + 2], wv[2], d);
                d = fmaf(z[c + 3], wv[3], d);
            }
            bu = zn - 2.0f * d;
            bk = k;
        }
    } else {
        // fallback: exact scan of all K (cold: only on survivor-list overflow)
        for (int k = l; k < K_ENT; k += 64) {
            const float* cr = cb + (size_t)k * 256;
            float d = 0.f;
            for (int c = 0; c < 256; c += 4) {
                floatx4 wv = *(const floatx4*)(cr + c);
                d = fmaf(z[c], wv[0], d);
                d = fmaf(z[c + 1], wv[1], d);
                d = fmaf(z[c + 2], wv[2], d);
                d = fmaf(z[c + 3], wv[3], d);
            }
            float u = zn - 2.0f * d;
            if (u < bu) { bu = u; bk = k; }   // ascending k keeps first min
        }
    }
#pragma unroll
    for (int msk = 1; msk < 64; msk <<= 1) {
        float ou = __shfl_xor(bu, msk);
        int   ok = __shfl_xor(bk, msk);
        if (ou < bu || (ou == bu && ok < bk)) { bu = ou; bk = ok; }
    }
    if (l == 0) { idxi[n] = bk; idxf[n] = (float)bk; }
}

// Gather z_q to output (coalesced writes) + loss partial sums
__global__ __launch_bounds__(256) void k_gather(const float* __restrict__ zin,
                                                const float* __restrict__ cb,
                                                const int* __restrict__ idxi,
                                                float* __restrict__ out,
                                                double* __restrict__ acc) {
    __shared__ float wsum[4];
    int t = blockIdx.x * 256 + threadIdx.x;   // 2,097,152 threads, 4 elems each
    int o = t << 2;
    int b = o >> 20, rem = o & 1048575;
    int c = rem >> 12, sp = rem & 4095;
    int n = (b << 12) + sp;
    floatx4 z4 = *(const floatx4*)(zin + o);
    floatx4 v;
    float ls = 0.f;
#pragma unroll
    for (int i = 0; i < 4; ++i) {
        int k = idxi[n + i];
        float cv = cb[(size_t)k * 256 + c];
        v[i] = cv;
        float d = cv - z4[i];
        ls = fmaf(d, d, ls);
    }
    *(floatx4*)(out + o) = v;
#pragma unroll
    for (int msk = 1; msk < 64; msk <<= 1) ls += __shfl_xor(ls, msk);
    int w = threadIdx.x >> 6, l = threadIdx.x & 63;
    if (l == 0) wsum[w] = ls;
    __syncthreads();
    if (threadIdx.x == 0) {
        float tot = (wsum[0] + wsum[1]) + (wsum[2] + wsum[3]);
        atomicAdd(acc, (double)tot);
    }
}

__global__ void k_fin(const double* __restrict__ acc, float* __restrict__ out) {
    out[LOSS_OFF] = (float)(2.0 * (*acc) / 8388608.0);
}

extern "C" void kernel_launch(void* const* d_in, const int* in_sizes, int n_in,
                              void* d_out, int out_size, void* d_ws, size_t ws_size,
                              hipStream_t stream) {
    (void)in_sizes; (void)n_in; (void)out_size;
    const float* z  = (const float*)d_in[0];
    const float* cb = (const float*)d_in[1];
    float* out = (float*)d_out;
    char* ws = (char*)d_ws;

    size_t off = 0;
    ushort_t* zsw  = (ushort_t*)(ws + off); off += 16777216;   // bf16 swizzled z
    ushort_t* cbsw = (ushort_t*)(ws + off); off += 4194304;    // bf16 swizzled codebook
    float* ztf = nullptr;
    const size_t ZTF_BYTES = 33554432;                          // fp32 transposed z
    const size_t TAIL = 4194304 + 131072 + 131072 + 8;
    if (ws_size >= off + ZTF_BYTES + TAIL) { ztf = (float*)(ws + off); off += ZTF_BYTES; }
    int* surv = (int*)(ws + off); off += 4194304;
    int* cnt  = (int*)(ws + off); off += 131072;
    int* idxi = (int*)(ws + off); off += 131072;
    double* acc = (double*)(ws + off);

    k_init<<<128, 256, 0, stream>>>(cnt, acc);
    k_conv_cb<<<1024, 256, 0, stream>>>(cb, cbsw);
    k_conv_z<<<2048, 256, 0, stream>>>(z, zsw, ztf);
    k_screen<<<512, 256, 0, stream>>>(zsw, cbsw, surv, cnt);
    k_refine<<<8192, 256, 0, stream>>>(z, ztf, cb, surv, cnt, idxi, out + IDX_OFF);
    k_gather<<<8192, 256, 0, stream>>>(z, cb, idxi, out, acc);
    k_fin<<<1, 1, 0, stream>>>(acc, out);
}